// Round 4
// baseline (13735.217 us; speedup 1.0000x reference)
//
#include <hip/hip_runtime.h>
#include <math.h>

// Problem constants
#define BB 4
#define CINC 256
#define COUTC 128
#define HH 64
#define WW 64
#define OHH 128
#define OWW 128

typedef unsigned short u16;

__device__ __forceinline__ float bf2f(u16 v) {
  return __uint_as_float(((unsigned int)v) << 16);
}
__device__ __forceinline__ u16 f2bf(float f) {
  unsigned int u = __float_as_uint(f);
  unsigned int r = u + 0x7FFFu + ((u >> 16) & 1u);  // RNE
  return (u16)(r >> 16);
}
// dtype-adaptive load: isf=1 -> float32 buffer, isf=0 -> bf16(u16) buffer
__device__ __forceinline__ float ld(const void* p, int i, int isf) {
  return isf ? ((const float*)p)[i] : bf2f(((const u16*)p)[i]);
}

// ---------------- K_flag: detect input dtype from bn1_g (= ones(128)).
// f32: first u32 = 0x3F800000. bf16-packed: first u32 = 0x3F803F80.
__global__ void kflag(const void* __restrict__ bn1_g, int* __restrict__ flag) {
  flag[0] = (((const unsigned int*)bn1_g)[0] == 0x3F800000u) ? 1 : 0;
}

// ---------------- K1: offset conv, one thread per (b, oc, h, w), oc in [0,27)
__global__ __launch_bounds__(256) void k1s(const void* __restrict__ x,
                                           const void* __restrict__ off_w,
                                           const void* __restrict__ off_b,
                                           const int* __restrict__ flagp,
                                           float* __restrict__ pyg,
                                           float* __restrict__ pxg,
                                           float* __restrict__ mg) {
  int isf = flagp[0];
  int tid = blockIdx.x * 256 + threadIdx.x;
  if (tid >= BB * 27 * HH * WW) return;
  int w = tid & 63;
  int h = (tid >> 6) & 63;
  int oc = (tid >> 12) % 27;
  int b = tid / (27 * 4096);

  float acc = 0.f;
  for (int c = 0; c < CINC; c++) {
    int xbase = (b * CINC + c) * (HH * WW);
    int wbase = (oc * CINC + c) * 9;
    for (int ky = 0; ky < 3; ky++) {
      int row = h + ky - 1;
      if (row < 0 || row >= HH) continue;
      for (int kx = 0; kx < 3; kx++) {
        int col = w + kx - 1;
        if (col < 0 || col >= WW) continue;
        acc = fmaf(ld(x, xbase + row * WW + col, isf), ld(off_w, wbase + ky * 3 + kx, isf), acc);
      }
    }
  }
  acc += ld(off_b, oc, isf);

  int k = oc % 9;
  int gi = ((b * 9 + k) * HH + h) * WW + w;
  if (oc < 9) {
    pyg[gi] = acc + (float)(oc / 3) - 1.f + (float)h;
  } else if (oc < 18) {
    pxg[gi] = acc + (float)((oc - 9) % 3) - 1.f + (float)w;
  } else {
    mg[gi] = 1.f / (1.f + expf(-acc));
  }
}

// ---------------- K2: deformable conv, one thread per (b, o, h, w)
__global__ __launch_bounds__(256) void k2s(const void* __restrict__ x,
                                           const void* __restrict__ dcn_w,
                                           const void* __restrict__ dcn_b,
                                           const int* __restrict__ flagp,
                                           const float* __restrict__ pyg,
                                           const float* __restrict__ pxg,
                                           const float* __restrict__ mg,
                                           float* __restrict__ out1) {
  int isf = flagp[0];
  int tid = blockIdx.x * 256 + threadIdx.x;
  if (tid >= BB * COUTC * HH * WW) return;
  int w = tid & 63;
  int h = (tid >> 6) & 63;
  int o = (tid >> 12) & 127;
  int b = tid >> 19;

  int xb = b * CINC * (HH * WW);
  float acc = 0.f;
  for (int k = 0; k < 9; k++) {
    int gi = ((b * 9 + k) * HH + h) * WW + w;
    float py = pyg[gi], px = pxg[gi], m = mg[gi];
    float y0f = floorf(py), x0f = floorf(px);
    float wy = py - y0f, wx = px - x0f;
    int y0 = (int)y0f, x0 = (int)x0f;
    float w00 = (1.f - wy) * (1.f - wx);
    float w01 = (1.f - wy) * wx;
    float w10 = wy * (1.f - wx);
    float w11 = wy * wx;
    bool vy0 = (y0 >= 0) & (y0 < HH);
    bool vy1 = (y0 + 1 >= 0) & (y0 + 1 < HH);
    bool vx0 = (x0 >= 0) & (x0 < WW);
    bool vx1 = (x0 + 1 >= 0) & (x0 + 1 < WW);
    int wpb = o * CINC * 9 + k;
    for (int c = 0; c < CINC; c++) {
      int xp = xb + c * (HH * WW);
      float s = 0.f;
      if (vy0 && vx0) s = fmaf(w00, ld(x, xp + y0 * WW + x0, isf), s);
      if (vy0 && vx1) s = fmaf(w01, ld(x, xp + y0 * WW + x0 + 1, isf), s);
      if (vy1 && vx0) s = fmaf(w10, ld(x, xp + (y0 + 1) * WW + x0, isf), s);
      if (vy1 && vx1) s = fmaf(w11, ld(x, xp + (y0 + 1) * WW + x0 + 1, isf), s);
      acc = fmaf(s * m, ld(dcn_w, wpb + c * 9, isf), acc);
    }
  }
  out1[tid] = acc + ld(dcn_b, o, isf);
}

// ---------------- K3/K5: per-channel two-pass BN stats
__global__ __launch_bounds__(256) void k3_stats1(const float* __restrict__ out1,
                                                 const void* __restrict__ g, const void* __restrict__ bt,
                                                 const int* __restrict__ flagp,
                                                 float* __restrict__ scale, float* __restrict__ shift) {
  int isf = flagp[0];
  int c = blockIdx.x, t = threadIdx.x;
  __shared__ float r1[256];
  __shared__ float muS;
  float s = 0.f;
  for (int e = t; e < BB * HH * WW; e += 256) {
    int b = e >> 12, sp = e & 4095;
    s += out1[(b * COUTC + c) * 4096 + sp];
  }
  r1[t] = s;
  __syncthreads();
  for (int off = 128; off > 0; off >>= 1) {
    if (t < off) r1[t] += r1[t + off];
    __syncthreads();
  }
  if (t == 0) muS = r1[0] / 16384.f;
  __syncthreads();
  float mu = muS;
  __syncthreads();
  float s2 = 0.f;
  for (int e = t; e < BB * HH * WW; e += 256) {
    int b = e >> 12, sp = e & 4095;
    float d = out1[(b * COUTC + c) * 4096 + sp] - mu;
    s2 += d * d;
  }
  r1[t] = s2;
  __syncthreads();
  for (int off = 128; off > 0; off >>= 1) {
    if (t < off) r1[t] += r1[t + off];
    __syncthreads();
  }
  if (t == 0) {
    float var = r1[0] / 16384.f;
    float sc = ld(g, c, isf) * rsqrtf(var + 1e-5f);
    scale[c] = sc;
    shift[c] = ld(bt, c, isf) - mu * sc;
  }
}

__global__ __launch_bounds__(256) void k5_stats2(const float* __restrict__ out2,
                                                 const void* __restrict__ g, const void* __restrict__ bt,
                                                 const int* __restrict__ flagp,
                                                 float* __restrict__ scale, float* __restrict__ shift) {
  int isf = flagp[0];
  int c = blockIdx.x, t = threadIdx.x;
  __shared__ float r1[256];
  __shared__ float muS;
  float s = 0.f;
  for (int e = t; e < BB * OHH * OWW; e += 256) {
    int b = e >> 14, sp = e & 16383;
    s += out2[(b * COUTC + c) * 16384 + sp];
  }
  r1[t] = s;
  __syncthreads();
  for (int off = 128; off > 0; off >>= 1) {
    if (t < off) r1[t] += r1[t + off];
    __syncthreads();
  }
  if (t == 0) muS = r1[0] / 65536.f;
  __syncthreads();
  float mu = muS;
  __syncthreads();
  float s2 = 0.f;
  for (int e = t; e < BB * OHH * OWW; e += 256) {
    int b = e >> 14, sp = e & 16383;
    float d = out2[(b * COUTC + c) * 16384 + sp] - mu;
    s2 += d * d;
  }
  r1[t] = s2;
  __syncthreads();
  for (int off = 128; off > 0; off >>= 1) {
    if (t < off) r1[t] += r1[t + off];
    __syncthreads();
  }
  if (t == 0) {
    float var = r1[0] / 65536.f;
    float sc = ld(g, c, isf) * rsqrtf(var + 1e-5f);
    scale[c] = sc;
    shift[c] = ld(bt, c, isf) - mu * sc;
  }
}

// ---------------- K4: bn1+relu fused transposed conv, one thread per (b, o, oh, ow)
__global__ __launch_bounds__(256) void k4s(const float* __restrict__ out1,
                                           const float* __restrict__ s1,
                                           const float* __restrict__ sh1,
                                           const void* __restrict__ up_w,
                                           const int* __restrict__ flagp,
                                           float* __restrict__ out2) {
  int isf = flagp[0];
  int tid = blockIdx.x * 256 + threadIdx.x;
  if (tid >= BB * COUTC * OHH * OWW) return;
  int ow = tid & 127;
  int oh = (tid >> 7) & 127;
  int o = (tid >> 14) & 127;
  int b = tid >> 21;

  float acc = 0.f;
  for (int ky = 0; ky < 4; ky++) {
    int p = oh + ky - 2;
    if (p < 0 || p > 126 || (p & 1)) continue;
    int m = p >> 1;
    for (int kx = 0; kx < 4; kx++) {
      int q = ow + kx - 2;
      if (q < 0 || q > 126 || (q & 1)) continue;
      int n = q >> 1;
      int woff = (3 - ky) * 4 + (3 - kx);                      // + (i*128+o)*16
      const float* ycol = out1 + (b * COUTC * HH + m) * WW + n; // + i*4096
      for (int i = 0; i < COUTC; i++) {
        float y = fmaxf(fmaf(ycol[i * (HH * WW)], s1[i], sh1[i]), 0.f);
        acc = fmaf(y, ld(up_w, (i * COUTC + o) * 16 + woff, isf), acc);
      }
    }
  }
  out2[tid] = acc;
}

// ---------------- K6: bn2+relu apply, dtype-adaptive store
__global__ __launch_bounds__(256) void k6s(const float* __restrict__ out2,
                                           const float* __restrict__ scale2,
                                           const float* __restrict__ shift2,
                                           const int* __restrict__ flagp,
                                           void* __restrict__ outp) {
  int isf = flagp[0];
  int tid = blockIdx.x * 256 + threadIdx.x;
  if (tid >= BB * COUTC * OHH * OWW) return;
  int c = (tid >> 14) & 127;
  float v = fmaxf(fmaf(out2[tid], scale2[c], shift2[c]), 0.f);
  if (isf) ((float*)outp)[tid] = v;
  else     ((u16*)outp)[tid] = f2bf(v);
}

// ---------------- launch
extern "C" void kernel_launch(void* const* d_in, const int* in_sizes, int n_in,
                              void* d_out, int out_size, void* d_ws, size_t ws_size,
                              hipStream_t stream) {
  const void* x     = d_in[0];
  const void* off_w = d_in[1];
  const void* off_b = d_in[2];
  const void* dcn_w = d_in[3];
  const void* dcn_b = d_in[4];
  const void* bn1_g = d_in[5];
  const void* bn1_b = d_in[6];
  const void* up_w  = d_in[7];
  const void* bn2_g = d_in[8];
  const void* bn2_b = d_in[9];

  float* ws = (float*)d_ws;
  float* pyg  = ws;                              // 147456
  float* pxg  = pyg + BB * 9 * HH * WW;          // 147456
  float* mg   = pxg + BB * 9 * HH * WW;          // 147456
  float* out1 = mg + BB * 9 * HH * WW;           // 2097152
  float* scale1 = out1 + BB * COUTC * HH * WW;   // 128
  float* shift1 = scale1 + 128;                  // 128
  float* out2 = shift1 + 128;                    // 8388608
  float* scale2 = out2 + BB * COUTC * OHH * OWW; // 128
  float* shift2 = scale2 + 128;                  // 128
  int* flagp = (int*)(shift2 + 128);             // 1

  const int N1 = BB * 27 * HH * WW;       // 442368
  const int N2 = BB * COUTC * HH * WW;    // 2097152
  const int N4 = BB * COUTC * OHH * OWW;  // 8388608

  kflag<<<1, 1, 0, stream>>>(bn1_g, flagp);
  k1s<<<(N1 + 255) / 256, 256, 0, stream>>>(x, off_w, off_b, flagp, pyg, pxg, mg);
  k2s<<<(N2 + 255) / 256, 256, 0, stream>>>(x, dcn_w, dcn_b, flagp, pyg, pxg, mg, out1);
  k3_stats1<<<COUTC, 256, 0, stream>>>(out1, bn1_g, bn1_b, flagp, scale1, shift1);
  k4s<<<(N4 + 255) / 256, 256, 0, stream>>>(out1, scale1, shift1, up_w, flagp, out2);
  k5_stats2<<<COUTC, 256, 0, stream>>>(out2, bn2_g, bn2_b, flagp, scale2, shift2);
  k6s<<<(N4 + 255) / 256, 256, 0, stream>>>(out2, scale2, shift2, flagp, d_out);
}

// Round 5
// 2752.126 us; speedup vs baseline: 4.9908x; 4.9908x over previous
//
#include <hip/hip_runtime.h>
#include <math.h>

// Problem constants
#define BB 4
#define CINC 256
#define COUTC 128
#define HH 64
#define WW 64
#define OHH 128
#define OWW 128

// ---------------- K0t: transpose dcn_w [o][c][q] -> w_t[(c*9+q)][o]  (ck-major, coalesced stage in k2f)
__global__ __launch_bounds__(256) void k0t(const float* __restrict__ dcn_w, float* __restrict__ w_t) {
  int tid = blockIdx.x * 256 + threadIdx.x;
  if (tid >= COUTC * CINC * 9) return;
  int ck = tid >> 7;        // 0..2303
  int o = tid & 127;
  w_t[tid] = dcn_w[o * (CINC * 9) + ck];
}

// ---------------- K1f: offset conv (tiled). grid (64,4)=(h,b), 256 thr.
// LDS x tile: 3 rows x 32 ch x 66 cols. Weights via wave-uniform scalar loads.
__global__ __launch_bounds__(256) void k1f(const float* __restrict__ x,
                                           const float* __restrict__ off_w,
                                           const float* __restrict__ off_b,
                                           float* __restrict__ pyg,
                                           float* __restrict__ pxg,
                                           float* __restrict__ mg) {
  int h = blockIdx.x, b = blockIdx.y;
  __shared__ float xs[3 * 32 * 66];
  int t = threadIdx.x;
  int tw = t & 63;
  int tg = __builtin_amdgcn_readfirstlane(t >> 6);  // wave id 0..3, uniform

  float acc[7];
#pragma unroll
  for (int j = 0; j < 7; j++) acc[j] = 0.f;

  for (int c0 = 0; c0 < CINC; c0 += 32) {
    __syncthreads();
    for (int e = t; e < 3 * 32 * 66; e += 256) {
      int r = e / (32 * 66);
      int rem = e - r * (32 * 66);
      int c = rem / 66;
      int wi = rem - c * 66;
      int row = h - 1 + r;
      int col = wi - 1;
      float v = 0.f;
      if (row >= 0 && row < HH && col >= 0 && col < WW)
        v = x[((b * CINC + c0 + c) * HH + row) * WW + col];
      xs[(r * 32 + c) * 66 + wi] = v;
    }
    __syncthreads();
    for (int c = 0; c < 32; c++) {
      float xv[9];
#pragma unroll
      for (int r = 0; r < 3; r++)
#pragma unroll
        for (int dx = 0; dx < 3; dx++)
          xv[r * 3 + dx] = xs[(r * 32 + c) * 66 + tw + dx];
#pragma unroll
      for (int j = 0; j < 7; j++) {
        int oc = tg + 4 * j;
        if (oc < 27) {
          const float* wp = off_w + (oc * CINC + c0 + c) * 9;  // uniform -> s_load
#pragma unroll
          for (int q = 0; q < 9; q++) acc[j] = fmaf(xv[q], wp[q], acc[j]);
        }
      }
    }
  }

#pragma unroll
  for (int j = 0; j < 7; j++) {
    int oc = tg + 4 * j;
    if (oc >= 27) continue;
    float v = acc[j] + off_b[oc];
    int k = oc % 9;
    int gi = ((b * 9 + k) * HH + h) * WW + tw;
    if (oc < 9) {
      pyg[gi] = v + (float)(oc / 3) - 1.f + (float)h;
    } else if (oc < 18) {
      pxg[gi] = v + (float)((oc - 9) % 3) - 1.f + (float)tw;
    } else {
      mg[gi] = 1.f / (1.f + expf(-v));
    }
  }
}

// ---------------- K2f: deformable conv as tiled GEMM. grid (2,64,4)=(whalf,h,b), 256 thr.
// S[ck, px] staged per 8-channel chunk (bilinear gather); W chunk staged ck-major from w_t.
// Thread tile 4 cout x 4 px.
__device__ __forceinline__ float sampf(const float* __restrict__ xp, int yi, int xi) {
  if (yi < 0 || yi >= HH || xi < 0 || xi >= WW) return 0.f;
  return xp[yi * WW + xi];
}

__global__ __launch_bounds__(256) void k2f(const float* __restrict__ x,
                                           const float* __restrict__ w_t,
                                           const float* __restrict__ dcn_b,
                                           const float* __restrict__ pyg,
                                           const float* __restrict__ pxg,
                                           const float* __restrict__ mg,
                                           float* __restrict__ out1) {
  int whalf = blockIdx.x, h = blockIdx.y, b = blockIdx.z;
  __shared__ __align__(16) float posS[3 * 288];    // py | px | m, each [9][32]
  __shared__ __align__(16) float scol[72 * 32];    // (8ch x 9k) x 32 px
  __shared__ __align__(16) float wlS[72 * 128];    // 72 ck x 128 cout
  int t = threadIdx.x;

  for (int e = t; e < 288; e += 256) {
    int k = e >> 5, wl = e & 31;
    int gi = ((b * 9 + k) * HH + h) * WW + whalf * 32 + wl;
    posS[e] = pyg[gi];
    posS[288 + e] = pxg[gi];
    posS[576 + e] = mg[gi];
  }

  float acc[4][4];
#pragma unroll
  for (int i = 0; i < 4; i++)
#pragma unroll
    for (int j = 0; j < 4; j++) acc[i][j] = 0.f;

  int co0 = (t >> 3) * 4;   // 0..124
  int w0 = (t & 7) * 4;     // 0..28
  const float* xpb = x + b * CINC * HH * WW;

  for (int c0 = 0; c0 < CINC; c0 += 8) {
    __syncthreads();
    // stage weights: contiguous from w_t (coalesced)
    const float* wsrc = w_t + c0 * 9 * 128;
    for (int e = t; e < 9216; e += 256) wlS[e] = wsrc[e];
    // stage samples: bilinear gather
    for (int e = t; e < 2304; e += 256) {
      int ck = e >> 5, wl = e & 31;
      int c = c0 + ck / 9;
      int k = ck % 9;
      float py = posS[k * 32 + wl];
      float px = posS[288 + k * 32 + wl];
      float m = posS[576 + k * 32 + wl];
      float y0f = floorf(py), x0f = floorf(px);
      float wy = py - y0f, wx = px - x0f;
      int y0 = (int)y0f, x0 = (int)x0f;
      const float* xp = xpb + c * HH * WW;
      float v00 = sampf(xp, y0, x0);
      float v01 = sampf(xp, y0, x0 + 1);
      float v10 = sampf(xp, y0 + 1, x0);
      float v11 = sampf(xp, y0 + 1, x0 + 1);
      float v = v00 * (1.f - wy) * (1.f - wx) + v01 * (1.f - wy) * wx +
                v10 * wy * (1.f - wx) + v11 * wy * wx;
      scol[ck * 32 + wl] = v * m;
    }
    __syncthreads();
#pragma unroll 8
    for (int ck = 0; ck < 72; ck++) {
      float4 sv = *(const float4*)&scol[ck * 32 + w0];
      float4 wv = *(const float4*)&wlS[ck * 128 + co0];
      acc[0][0] = fmaf(wv.x, sv.x, acc[0][0]); acc[0][1] = fmaf(wv.x, sv.y, acc[0][1]);
      acc[0][2] = fmaf(wv.x, sv.z, acc[0][2]); acc[0][3] = fmaf(wv.x, sv.w, acc[0][3]);
      acc[1][0] = fmaf(wv.y, sv.x, acc[1][0]); acc[1][1] = fmaf(wv.y, sv.y, acc[1][1]);
      acc[1][2] = fmaf(wv.y, sv.z, acc[1][2]); acc[1][3] = fmaf(wv.y, sv.w, acc[1][3]);
      acc[2][0] = fmaf(wv.z, sv.x, acc[2][0]); acc[2][1] = fmaf(wv.z, sv.y, acc[2][1]);
      acc[2][2] = fmaf(wv.z, sv.z, acc[2][2]); acc[2][3] = fmaf(wv.z, sv.w, acc[2][3]);
      acc[3][0] = fmaf(wv.w, sv.x, acc[3][0]); acc[3][1] = fmaf(wv.w, sv.y, acc[3][1]);
      acc[3][2] = fmaf(wv.w, sv.z, acc[3][2]); acc[3][3] = fmaf(wv.w, sv.w, acc[3][3]);
    }
  }

#pragma unroll
  for (int i = 0; i < 4; i++) {
    float bias = dcn_b[co0 + i];
    float4 o;
    o.x = acc[i][0] + bias; o.y = acc[i][1] + bias;
    o.z = acc[i][2] + bias; o.w = acc[i][3] + bias;
    *(float4*)&out1[((b * COUTC + co0 + i) * HH + h) * WW + whalf * 32 + w0] = o;
  }
}

// ---------------- K3/K5: per-channel two-pass BN stats
__global__ __launch_bounds__(256) void k3_stats1(const float* __restrict__ out1,
                                                 const float* __restrict__ g, const float* __restrict__ bt,
                                                 float* __restrict__ scale, float* __restrict__ shift) {
  int c = blockIdx.x, t = threadIdx.x;
  __shared__ float r1[256];
  __shared__ float muS;
  float s = 0.f;
  for (int e = t; e < BB * HH * WW; e += 256) {
    int b = e >> 12, sp = e & 4095;
    s += out1[(b * COUTC + c) * 4096 + sp];
  }
  r1[t] = s;
  __syncthreads();
  for (int off = 128; off > 0; off >>= 1) {
    if (t < off) r1[t] += r1[t + off];
    __syncthreads();
  }
  if (t == 0) muS = r1[0] / 16384.f;
  __syncthreads();
  float mu = muS;
  __syncthreads();
  float s2 = 0.f;
  for (int e = t; e < BB * HH * WW; e += 256) {
    int b = e >> 12, sp = e & 4095;
    float d = out1[(b * COUTC + c) * 4096 + sp] - mu;
    s2 += d * d;
  }
  r1[t] = s2;
  __syncthreads();
  for (int off = 128; off > 0; off >>= 1) {
    if (t < off) r1[t] += r1[t + off];
    __syncthreads();
  }
  if (t == 0) {
    float var = r1[0] / 16384.f;
    float sc = g[c] * rsqrtf(var + 1e-5f);
    scale[c] = sc;
    shift[c] = bt[c] - mu * sc;
  }
}

__global__ __launch_bounds__(256) void k5_stats2(const float* __restrict__ out2,
                                                 const float* __restrict__ g, const float* __restrict__ bt,
                                                 float* __restrict__ scale, float* __restrict__ shift) {
  int c = blockIdx.x, t = threadIdx.x;
  __shared__ float r1[256];
  __shared__ float muS;
  float s = 0.f;
  for (int e = t; e < BB * OHH * OWW; e += 256) {
    int b = e >> 14, sp = e & 16383;
    s += out2[(b * COUTC + c) * 16384 + sp];
  }
  r1[t] = s;
  __syncthreads();
  for (int off = 128; off > 0; off >>= 1) {
    if (t < off) r1[t] += r1[t + off];
    __syncthreads();
  }
  if (t == 0) muS = r1[0] / 65536.f;
  __syncthreads();
  float mu = muS;
  __syncthreads();
  float s2 = 0.f;
  for (int e = t; e < BB * OHH * OWW; e += 256) {
    int b = e >> 14, sp = e & 16383;
    float d = out2[(b * COUTC + c) * 16384 + sp] - mu;
    s2 += d * d;
  }
  r1[t] = s2;
  __syncthreads();
  for (int off = 128; off > 0; off >>= 1) {
    if (t < off) r1[t] += r1[t + off];
    __syncthreads();
  }
  if (t == 0) {
    float var = r1[0] / 65536.f;
    float sc = g[c] * rsqrtf(var + 1e-5f);
    scale[c] = sc;
    shift[c] = bt[c] - mu * sc;
  }
}

// ---------------- K4s: bn1+relu fused transposed conv (naive, validated). one thread per (b,o,oh,ow)
__global__ __launch_bounds__(256) void k4s(const float* __restrict__ out1,
                                           const float* __restrict__ s1,
                                           const float* __restrict__ sh1,
                                           const float* __restrict__ up_w,
                                           float* __restrict__ out2) {
  int tid = blockIdx.x * 256 + threadIdx.x;
  if (tid >= BB * COUTC * OHH * OWW) return;
  int ow = tid & 127;
  int oh = (tid >> 7) & 127;
  int o = (tid >> 14) & 127;
  int b = tid >> 21;

  float acc = 0.f;
  for (int ky = 0; ky < 4; ky++) {
    int p = oh + ky - 2;
    if (p < 0 || p > 126 || (p & 1)) continue;
    int m = p >> 1;
    for (int kx = 0; kx < 4; kx++) {
      int q = ow + kx - 2;
      if (q < 0 || q > 126 || (q & 1)) continue;
      int n = q >> 1;
      int woff = (3 - ky) * 4 + (3 - kx);                       // + (i*128+o)*16
      const float* ycol = out1 + (b * COUTC * HH + m) * WW + n;  // + i*4096
      for (int i = 0; i < COUTC; i++) {
        float y = fmaxf(fmaf(ycol[i * (HH * WW)], s1[i], sh1[i]), 0.f);
        acc = fmaf(y, up_w[(i * COUTC + o) * 16 + woff], acc);
      }
    }
  }
  out2[tid] = acc;
}

// ---------------- K6: bn2+relu apply (f32 out)
__global__ __launch_bounds__(256) void k6s(const float* __restrict__ out2,
                                           const float* __restrict__ scale2,
                                           const float* __restrict__ shift2,
                                           float* __restrict__ outp) {
  int tid = blockIdx.x * 256 + threadIdx.x;
  if (tid >= BB * COUTC * OHH * OWW) return;
  int c = (tid >> 14) & 127;
  outp[tid] = fmaxf(fmaf(out2[tid], scale2[c], shift2[c]), 0.f);
}

// ---------------- launch
extern "C" void kernel_launch(void* const* d_in, const int* in_sizes, int n_in,
                              void* d_out, int out_size, void* d_ws, size_t ws_size,
                              hipStream_t stream) {
  const float* x     = (const float*)d_in[0];
  const float* off_w = (const float*)d_in[1];
  const float* off_b = (const float*)d_in[2];
  const float* dcn_w = (const float*)d_in[3];
  const float* dcn_b = (const float*)d_in[4];
  const float* bn1_g = (const float*)d_in[5];
  const float* bn1_b = (const float*)d_in[6];
  const float* up_w  = (const float*)d_in[7];
  const float* bn2_g = (const float*)d_in[8];
  const float* bn2_b = (const float*)d_in[9];

  float* ws = (float*)d_ws;
  float* pyg  = ws;                              // 147456
  float* pxg  = pyg + BB * 9 * HH * WW;          // 147456
  float* mg   = pxg + BB * 9 * HH * WW;          // 147456
  float* out1 = mg + BB * 9 * HH * WW;           // 2097152
  float* scale1 = out1 + BB * COUTC * HH * WW;   // 128
  float* shift1 = scale1 + 128;                  // 128
  float* out2 = shift1 + 128;                    // 8388608
  float* scale2 = out2 + BB * COUTC * OHH * OWW; // 128
  float* shift2 = scale2 + 128;                  // 128
  float* w_t = shift2 + 128;                     // 294912

  const int N4 = BB * COUTC * OHH * OWW;  // 8388608

  k0t<<<(COUTC * CINC * 9 + 255) / 256, 256, 0, stream>>>(dcn_w, w_t);
  k1f<<<dim3(64, 4), 256, 0, stream>>>(x, off_w, off_b, pyg, pxg, mg);
  k2f<<<dim3(2, 64, 4), 256, 0, stream>>>(x, w_t, dcn_b, pyg, pxg, mg, out1);
  k3_stats1<<<COUTC, 256, 0, stream>>>(out1, bn1_g, bn1_b, scale1, shift1);
  k4s<<<(N4 + 255) / 256, 256, 0, stream>>>(out1, scale1, shift1, up_w, out2);
  k5_stats2<<<COUTC, 256, 0, stream>>>(out2, bn2_g, bn2_b, scale2, shift2);
  k6s<<<(N4 + 255) / 256, 256, 0, stream>>>(out2, scale2, shift2, (float*)d_out);
}

// Round 6
// 1017.929 us; speedup vs baseline: 13.4933x; 2.7037x over previous
//
#include <hip/hip_runtime.h>
#include <math.h>

// Problem constants
#define BB 4
#define CINC 256
#define COUTC 128
#define HH 64
#define WW 64
#define OHH 128
#define OWW 128

// ---------------- K0t: transpose dcn_w [o][c][q] -> w_t[(c*9+q)][o]  (ck-major, coalesced stage in k2f)
__global__ __launch_bounds__(256) void k0t(const float* __restrict__ dcn_w, float* __restrict__ w_t) {
  int tid = blockIdx.x * 256 + threadIdx.x;
  if (tid >= COUTC * CINC * 9) return;
  int ck = tid >> 7;        // 0..2303
  int o = tid & 127;
  w_t[tid] = dcn_w[o * (CINC * 9) + ck];
}

// ---------------- K0u: transpose up_w -> wt4[tt][i][o][s]  (s fastest -> float4/lane, o lane-contig)
// wt4[((tt*128 + i)*128 + o)*4 + s] = wf[o,i,tt,s] = up_w[((i*128 + o)*4 + (3-tt))*4 + (3-s)]
__global__ __launch_bounds__(256) void k0u(const float* __restrict__ up_w, float* __restrict__ wt4) {
  int tid = blockIdx.x * 256 + threadIdx.x;
  if (tid >= 4 * COUTC * COUTC * 4) return;
  int s = tid & 3;
  int o = (tid >> 2) & 127;
  int i = (tid >> 9) & 127;
  int tt = tid >> 16;
  wt4[tid] = up_w[((i * COUTC + o) * 4 + (3 - tt)) * 4 + (3 - s)];
}

// ---------------- K1f: offset conv (tiled). grid (64,4)=(h,b), 256 thr.
__global__ __launch_bounds__(256) void k1f(const float* __restrict__ x,
                                           const float* __restrict__ off_w,
                                           const float* __restrict__ off_b,
                                           float* __restrict__ pyg,
                                           float* __restrict__ pxg,
                                           float* __restrict__ mg) {
  int h = blockIdx.x, b = blockIdx.y;
  __shared__ float xs[3 * 32 * 66];
  int t = threadIdx.x;
  int tw = t & 63;
  int tg = __builtin_amdgcn_readfirstlane(t >> 6);  // wave id 0..3, uniform

  float acc[7];
#pragma unroll
  for (int j = 0; j < 7; j++) acc[j] = 0.f;

  for (int c0 = 0; c0 < CINC; c0 += 32) {
    __syncthreads();
    for (int e = t; e < 3 * 32 * 66; e += 256) {
      int r = e / (32 * 66);
      int rem = e - r * (32 * 66);
      int c = rem / 66;
      int wi = rem - c * 66;
      int row = h - 1 + r;
      int col = wi - 1;
      float v = 0.f;
      if (row >= 0 && row < HH && col >= 0 && col < WW)
        v = x[((b * CINC + c0 + c) * HH + row) * WW + col];
      xs[(r * 32 + c) * 66 + wi] = v;
    }
    __syncthreads();
    for (int c = 0; c < 32; c++) {
      float xv[9];
#pragma unroll
      for (int r = 0; r < 3; r++)
#pragma unroll
        for (int dx = 0; dx < 3; dx++)
          xv[r * 3 + dx] = xs[(r * 32 + c) * 66 + tw + dx];
#pragma unroll
      for (int j = 0; j < 7; j++) {
        int oc = tg + 4 * j;
        if (oc < 27) {
          const float* wp = off_w + (oc * CINC + c0 + c) * 9;  // uniform -> s_load
#pragma unroll
          for (int q = 0; q < 9; q++) acc[j] = fmaf(xv[q], wp[q], acc[j]);
        }
      }
    }
  }

#pragma unroll
  for (int j = 0; j < 7; j++) {
    int oc = tg + 4 * j;
    if (oc >= 27) continue;
    float v = acc[j] + off_b[oc];
    int k = oc % 9;
    int gi = ((b * 9 + k) * HH + h) * WW + tw;
    if (oc < 9) {
      pyg[gi] = v + (float)(oc / 3) - 1.f + (float)h;
    } else if (oc < 18) {
      pxg[gi] = v + (float)((oc - 9) % 3) - 1.f + (float)tw;
    } else {
      mg[gi] = 1.f / (1.f + expf(-v));
    }
  }
}

// ---------------- K2f: deformable conv as tiled GEMM. grid (2,64,4)=(whalf,h,b), 256 thr.
__device__ __forceinline__ float sampf(const float* __restrict__ xp, int yi, int xi) {
  if (yi < 0 || yi >= HH || xi < 0 || xi >= WW) return 0.f;
  return xp[yi * WW + xi];
}

__global__ __launch_bounds__(256) void k2f(const float* __restrict__ x,
                                           const float* __restrict__ w_t,
                                           const float* __restrict__ dcn_b,
                                           const float* __restrict__ pyg,
                                           const float* __restrict__ pxg,
                                           const float* __restrict__ mg,
                                           float* __restrict__ out1) {
  int whalf = blockIdx.x, h = blockIdx.y, b = blockIdx.z;
  __shared__ __align__(16) float posS[3 * 288];    // py | px | m, each [9][32]
  __shared__ __align__(16) float scol[72 * 32];    // (8ch x 9k) x 32 px
  __shared__ __align__(16) float wlS[72 * 128];    // 72 ck x 128 cout
  int t = threadIdx.x;

  for (int e = t; e < 288; e += 256) {
    int k = e >> 5, wl = e & 31;
    int gi = ((b * 9 + k) * HH + h) * WW + whalf * 32 + wl;
    posS[e] = pyg[gi];
    posS[288 + e] = pxg[gi];
    posS[576 + e] = mg[gi];
  }

  float acc[4][4];
#pragma unroll
  for (int i = 0; i < 4; i++)
#pragma unroll
    for (int j = 0; j < 4; j++) acc[i][j] = 0.f;

  int co0 = (t >> 3) * 4;   // 0..124
  int w0 = (t & 7) * 4;     // 0..28
  const float* xpb = x + b * CINC * HH * WW;

  for (int c0 = 0; c0 < CINC; c0 += 8) {
    __syncthreads();
    const float* wsrc = w_t + c0 * 9 * 128;
    for (int e = t; e < 9216; e += 256) wlS[e] = wsrc[e];
    for (int e = t; e < 2304; e += 256) {
      int ck = e >> 5, wl = e & 31;
      int c = c0 + ck / 9;
      int k = ck % 9;
      float py = posS[k * 32 + wl];
      float px = posS[288 + k * 32 + wl];
      float m = posS[576 + k * 32 + wl];
      float y0f = floorf(py), x0f = floorf(px);
      float wy = py - y0f, wx = px - x0f;
      int y0 = (int)y0f, x0 = (int)x0f;
      const float* xp = xpb + c * HH * WW;
      float v00 = sampf(xp, y0, x0);
      float v01 = sampf(xp, y0, x0 + 1);
      float v10 = sampf(xp, y0 + 1, x0);
      float v11 = sampf(xp, y0 + 1, x0 + 1);
      float v = v00 * (1.f - wy) * (1.f - wx) + v01 * (1.f - wy) * wx +
                v10 * wy * (1.f - wx) + v11 * wy * wx;
      scol[ck * 32 + wl] = v * m;
    }
    __syncthreads();
#pragma unroll 8
    for (int ck = 0; ck < 72; ck++) {
      float4 sv = *(const float4*)&scol[ck * 32 + w0];
      float4 wv = *(const float4*)&wlS[ck * 128 + co0];
      acc[0][0] = fmaf(wv.x, sv.x, acc[0][0]); acc[0][1] = fmaf(wv.x, sv.y, acc[0][1]);
      acc[0][2] = fmaf(wv.x, sv.z, acc[0][2]); acc[0][3] = fmaf(wv.x, sv.w, acc[0][3]);
      acc[1][0] = fmaf(wv.y, sv.x, acc[1][0]); acc[1][1] = fmaf(wv.y, sv.y, acc[1][1]);
      acc[1][2] = fmaf(wv.y, sv.z, acc[1][2]); acc[1][3] = fmaf(wv.y, sv.w, acc[1][3]);
      acc[2][0] = fmaf(wv.z, sv.x, acc[2][0]); acc[2][1] = fmaf(wv.z, sv.y, acc[2][1]);
      acc[2][2] = fmaf(wv.z, sv.z, acc[2][2]); acc[2][3] = fmaf(wv.z, sv.w, acc[2][3]);
      acc[3][0] = fmaf(wv.w, sv.x, acc[3][0]); acc[3][1] = fmaf(wv.w, sv.y, acc[3][1]);
      acc[3][2] = fmaf(wv.w, sv.z, acc[3][2]); acc[3][3] = fmaf(wv.w, sv.w, acc[3][3]);
    }
  }

#pragma unroll
  for (int i = 0; i < 4; i++) {
    float bias = dcn_b[co0 + i];
    float4 o;
    o.x = acc[i][0] + bias; o.y = acc[i][1] + bias;
    o.z = acc[i][2] + bias; o.w = acc[i][3] + bias;
    *(float4*)&out1[((b * COUTC + co0 + i) * HH + h) * WW + whalf * 32 + w0] = o;
  }
}

// ---------------- K3/K5: per-channel two-pass BN stats
__global__ __launch_bounds__(256) void k3_stats1(const float* __restrict__ out1,
                                                 const float* __restrict__ g, const float* __restrict__ bt,
                                                 float* __restrict__ scale, float* __restrict__ shift) {
  int c = blockIdx.x, t = threadIdx.x;
  __shared__ float r1[256];
  __shared__ float muS;
  float s = 0.f;
  for (int e = t; e < BB * HH * WW; e += 256) {
    int b = e >> 12, sp = e & 4095;
    s += out1[(b * COUTC + c) * 4096 + sp];
  }
  r1[t] = s;
  __syncthreads();
  for (int off = 128; off > 0; off >>= 1) {
    if (t < off) r1[t] += r1[t + off];
    __syncthreads();
  }
  if (t == 0) muS = r1[0] / 16384.f;
  __syncthreads();
  float mu = muS;
  __syncthreads();
  float s2 = 0.f;
  for (int e = t; e < BB * HH * WW; e += 256) {
    int b = e >> 12, sp = e & 4095;
    float d = out1[(b * COUTC + c) * 4096 + sp] - mu;
    s2 += d * d;
  }
  r1[t] = s2;
  __syncthreads();
  for (int off = 128; off > 0; off >>= 1) {
    if (t < off) r1[t] += r1[t + off];
    __syncthreads();
  }
  if (t == 0) {
    float var = r1[0] / 16384.f;
    float sc = g[c] * rsqrtf(var + 1e-5f);
    scale[c] = sc;
    shift[c] = bt[c] - mu * sc;
  }
}

__global__ __launch_bounds__(256) void k5_stats2(const float* __restrict__ out2,
                                                 const float* __restrict__ g, const float* __restrict__ bt,
                                                 float* __restrict__ scale, float* __restrict__ shift) {
  int c = blockIdx.x, t = threadIdx.x;
  __shared__ float r1[256];
  __shared__ float muS;
  float s = 0.f;
  for (int e = t; e < BB * OHH * OWW; e += 256) {
    int b = e >> 14, sp = e & 16383;
    s += out2[(b * COUTC + c) * 16384 + sp];
  }
  r1[t] = s;
  __syncthreads();
  for (int off = 128; off > 0; off >>= 1) {
    if (t < off) r1[t] += r1[t + off];
    __syncthreads();
  }
  if (t == 0) muS = r1[0] / 65536.f;
  __syncthreads();
  float mu = muS;
  __syncthreads();
  float s2 = 0.f;
  for (int e = t; e < BB * OHH * OWW; e += 256) {
    int b = e >> 14, sp = e & 16383;
    float d = out2[(b * COUTC + c) * 16384 + sp] - mu;
    s2 += d * d;
  }
  r1[t] = s2;
  __syncthreads();
  for (int off = 128; off > 0; off >>= 1) {
    if (t < off) r1[t] += r1[t + off];
    __syncthreads();
  }
  if (t == 0) {
    float var = r1[0] / 65536.f;
    float sc = g[c] * rsqrtf(var + 1e-5f);
    scale[c] = sc;
    shift[c] = bt[c] - mu * sc;
  }
}

// ---------------- K4f: bn1+relu fused transposed conv (tiled, parity-decomposed).
// grid (128,4)=(oh,b), 256 thr. thread: o=t>>1, half=t&1, 64 acc.
// ys LDS reads are wave-broadcast (address independent of o) -> conflict-free.
__global__ __launch_bounds__(256) void k4f(const float* __restrict__ out1,
                                           const float* __restrict__ s1,
                                           const float* __restrict__ sh1,
                                           const float* __restrict__ wt4,
                                           float* __restrict__ out2) {
  int oh = blockIdx.x, b = blockIdx.y;
  __shared__ __align__(16) float ys[2 * 128 * 64];  // exactly 64 KiB
  int t = threadIdx.x;
  int t0 = oh & 1;  // tap parity

  // stage 2 bn-relu'd input rows (vectorized float4)
#pragma unroll
  for (int ti = 0; ti < 2; ti++) {
    int tt = t0 + 2 * ti;
    int m = (oh + tt - 2) / 2;  // exact (numerator even)
    bool rowok = (m >= 0 && m < 64);
    for (int e = t; e < 2048; e += 256) {
      int i = e >> 4;           // 16 float4 per i-row
      float4 v = make_float4(0.f, 0.f, 0.f, 0.f);
      if (rowok) {
        float4 r = *(const float4*)&out1[((b * COUTC + i) * HH + m) * WW + (e & 15) * 4];
        float sc = s1[i], sh = sh1[i];
        v.x = fmaxf(fmaf(r.x, sc, sh), 0.f);
        v.y = fmaxf(fmaf(r.y, sc, sh), 0.f);
        v.z = fmaxf(fmaf(r.z, sc, sh), 0.f);
        v.w = fmaxf(fmaf(r.w, sc, sh), 0.f);
      }
      *(float4*)&ys[ti * 8192 + e * 4] = v;
    }
  }
  __syncthreads();

  int o = t >> 1, half = t & 1;
  int nb = half * 32;
  float acc[64];
#pragma unroll
  for (int j = 0; j < 64; j++) acc[j] = 0.f;

  const float* wb0 = wt4 + ((t0 * 128) * 128 + o) * 4;        // ti=0 base
  const float* wb1 = wt4 + (((t0 + 2) * 128) * 128 + o) * 4;  // ti=1 base

  for (int i = 0; i < 128; i++) {
#pragma unroll
    for (int ti = 0; ti < 2; ti++) {
      float4 wv = *(const float4*)((ti ? wb1 : wb0) + i * 512);  // coalesced dwordx4
      float W0 = wv.x, W1 = wv.y, W2 = wv.z, W3 = wv.w;

      const float* yb = &ys[ti * 8192 + i * 64 + nb];
      float yv[34];
#pragma unroll
      for (int j4 = 0; j4 < 8; j4++) {
        float4 q4 = *(const float4*)(yb + 4 * j4);
        yv[1 + 4 * j4] = q4.x; yv[2 + 4 * j4] = q4.y;
        yv[3 + 4 * j4] = q4.z; yv[4 + 4 * j4] = q4.w;
      }
      yv[0]  = half ? yb[-1] : 0.f;   // y[v-1] at v=half*32
      yv[33] = half ? 0.f : yb[32];   // y[v+1] at v=half*32+31
#pragma unroll
      for (int u = 0; u < 32; u++) {
        acc[2 * u]     = fmaf(W0, yv[u],     fmaf(W2, yv[u + 1], acc[2 * u]));
        acc[2 * u + 1] = fmaf(W1, yv[u + 1], fmaf(W3, yv[u + 2], acc[2 * u + 1]));
      }
    }
  }

  float* op = out2 + ((b * COUTC + o) * OHH + oh) * OWW + half * 64;
#pragma unroll
  for (int j4 = 0; j4 < 16; j4++) {
    float4 v;
    v.x = acc[4 * j4]; v.y = acc[4 * j4 + 1]; v.z = acc[4 * j4 + 2]; v.w = acc[4 * j4 + 3];
    *(float4*)&op[4 * j4] = v;
  }
}

// ---------------- K6: bn2+relu apply (f32 out)
__global__ __launch_bounds__(256) void k6s(const float* __restrict__ out2,
                                           const float* __restrict__ scale2,
                                           const float* __restrict__ shift2,
                                           float* __restrict__ outp) {
  int tid = blockIdx.x * 256 + threadIdx.x;
  if (tid >= BB * COUTC * OHH * OWW) return;
  int c = (tid >> 14) & 127;
  outp[tid] = fmaxf(fmaf(out2[tid], scale2[c], shift2[c]), 0.f);
}

// ---------------- launch
extern "C" void kernel_launch(void* const* d_in, const int* in_sizes, int n_in,
                              void* d_out, int out_size, void* d_ws, size_t ws_size,
                              hipStream_t stream) {
  const float* x     = (const float*)d_in[0];
  const float* off_w = (const float*)d_in[1];
  const float* off_b = (const float*)d_in[2];
  const float* dcn_w = (const float*)d_in[3];
  const float* dcn_b = (const float*)d_in[4];
  const float* bn1_g = (const float*)d_in[5];
  const float* bn1_b = (const float*)d_in[6];
  const float* up_w  = (const float*)d_in[7];
  const float* bn2_g = (const float*)d_in[8];
  const float* bn2_b = (const float*)d_in[9];

  float* ws = (float*)d_ws;
  float* pyg  = ws;                              // 147456
  float* pxg  = pyg + BB * 9 * HH * WW;          // 147456
  float* mg   = pxg + BB * 9 * HH * WW;          // 147456
  float* out1 = mg + BB * 9 * HH * WW;           // 2097152
  float* scale1 = out1 + BB * COUTC * HH * WW;   // 128
  float* shift1 = scale1 + 128;                  // 128
  float* out2 = shift1 + 128;                    // 8388608
  float* scale2 = out2 + BB * COUTC * OHH * OWW; // 128
  float* shift2 = scale2 + 128;                  // 128
  float* w_t = shift2 + 128;                     // 294912
  float* wt4 = w_t + COUTC * CINC * 9;           // 262144

  const int N4 = BB * COUTC * OHH * OWW;  // 8388608

  k0t<<<(COUTC * CINC * 9 + 255) / 256, 256, 0, stream>>>(dcn_w, w_t);
  k0u<<<(4 * COUTC * COUTC * 4 + 255) / 256, 256, 0, stream>>>(up_w, wt4);
  k1f<<<dim3(64, 4), 256, 0, stream>>>(x, off_w, off_b, pyg, pxg, mg);
  k2f<<<dim3(2, 64, 4), 256, 0, stream>>>(x, w_t, dcn_b, pyg, pxg, mg, out1);
  k3_stats1<<<COUTC, 256, 0, stream>>>(out1, bn1_g, bn1_b, scale1, shift1);
  k4f<<<dim3(128, 4), 256, 0, stream>>>(out1, scale1, shift1, wt4, out2);
  k5_stats2<<<COUTC, 256, 0, stream>>>(out2, bn2_g, bn2_b, scale2, shift2);
  k6s<<<(N4 + 255) / 256, 256, 0, stream>>>(out2, scale2, shift2, (float*)d_out);
}

// Round 7
// 769.246 us; speedup vs baseline: 17.8554x; 1.3233x over previous
//
#include <hip/hip_runtime.h>
#include <math.h>

// Problem constants
#define BB 4
#define CINC 256
#define COUTC 128
#define HH 64
#define WW 64
#define OHH 128
#define OWW 128

// ---------------- K0t: transpose dcn_w [o][c][q] -> w_t[(c*9+q)][o]
__global__ __launch_bounds__(256) void k0t(const float* __restrict__ dcn_w, float* __restrict__ w_t) {
  int tid = blockIdx.x * 256 + threadIdx.x;
  if (tid >= COUTC * CINC * 9) return;
  int ck = tid >> 7;
  int o = tid & 127;
  w_t[tid] = dcn_w[o * (CINC * 9) + ck];
}

// ---------------- K0u: transpose up_w -> wt4[tt][i][o][s]
__global__ __launch_bounds__(256) void k0u(const float* __restrict__ up_w, float* __restrict__ wt4) {
  int tid = blockIdx.x * 256 + threadIdx.x;
  if (tid >= 4 * COUTC * COUTC * 4) return;
  int s = tid & 3;
  int o = (tid >> 2) & 127;
  int i = (tid >> 9) & 127;
  int tt = tid >> 16;
  wt4[tid] = up_w[((i * COUTC + o) * 4 + (3 - tt)) * 4 + (3 - s)];
}

// ---------------- K1p: offset conv split-K partials. grid (4,64,4)=(cc,h,b), 256 thr.
// Each block: 64 input channels (2 LDS chunks of 32), partial om[27][64] -> part.
__global__ __launch_bounds__(256) void k1p(const float* __restrict__ x,
                                           const float* __restrict__ off_w,
                                           float* __restrict__ part) {
  int cc = blockIdx.x, h = blockIdx.y, b = blockIdx.z;
  __shared__ float xs[3 * 32 * 66];
  int t = threadIdx.x;
  int tw = t & 63;
  int tg = __builtin_amdgcn_readfirstlane(t >> 6);  // wave id 0..3, uniform

  float acc[7];
#pragma unroll
  for (int j = 0; j < 7; j++) acc[j] = 0.f;

  for (int cs = 0; cs < 2; cs++) {
    int c0 = cc * 64 + cs * 32;
    __syncthreads();
    for (int e = t; e < 3 * 32 * 66; e += 256) {
      int r = e / (32 * 66);
      int rem = e - r * (32 * 66);
      int c = rem / 66;
      int wi = rem - c * 66;
      int row = h - 1 + r;
      int col = wi - 1;
      float v = 0.f;
      if (row >= 0 && row < HH && col >= 0 && col < WW)
        v = x[((b * CINC + c0 + c) * HH + row) * WW + col];
      xs[(r * 32 + c) * 66 + wi] = v;
    }
    __syncthreads();
    for (int c = 0; c < 32; c++) {
      float xv[9];
#pragma unroll
      for (int r = 0; r < 3; r++)
#pragma unroll
        for (int dx = 0; dx < 3; dx++)
          xv[r * 3 + dx] = xs[(r * 32 + c) * 66 + tw + dx];
#pragma unroll
      for (int j = 0; j < 7; j++) {
        int oc = tg + 4 * j;
        if (oc < 27) {
          const float* wp = off_w + (oc * CINC + c0 + c) * 9;  // uniform -> s_load
#pragma unroll
          for (int q = 0; q < 9; q++) acc[j] = fmaf(xv[q], wp[q], acc[j]);
        }
      }
    }
  }

#pragma unroll
  for (int j = 0; j < 7; j++) {
    int oc = tg + 4 * j;
    if (oc < 27)
      part[((cc * BB + b) * 27 + oc) * 4096 + h * 64 + tw] = acc[j];
  }
}

// ---------------- K1r: reduce 4 partials + bias -> py/px/m
__global__ __launch_bounds__(256) void k1r(const float* __restrict__ part,
                                           const float* __restrict__ off_b,
                                           float* __restrict__ pyg,
                                           float* __restrict__ pxg,
                                           float* __restrict__ mg) {
  int tid = blockIdx.x * 256 + threadIdx.x;
  if (tid >= BB * 27 * HH * WW) return;
  int w = tid & 63;
  int h = (tid >> 6) & 63;
  int oc = (tid >> 12) % 27;
  int b = tid / (27 * 4096);
  int sp = tid & 4095;

  float v = off_b[oc];
#pragma unroll
  for (int cc = 0; cc < 4; cc++)
    v += part[((cc * BB + b) * 27 + oc) * 4096 + sp];

  int k = oc % 9;
  int gi = ((b * 9 + k) * HH + h) * WW + w;
  if (oc < 9) {
    pyg[gi] = v + (float)(oc / 3) - 1.f + (float)h;
  } else if (oc < 18) {
    pxg[gi] = v + (float)((oc - 9) % 3) - 1.f + (float)w;
  } else {
    mg[gi] = 1.f / (1.f + expf(-v));
  }
}

// ---------------- K2f: deformable conv as tiled GEMM. grid (2,64,4)=(whalf,h,b), 256 thr.
__device__ __forceinline__ float sampf(const float* __restrict__ xp, int yi, int xi) {
  if (yi < 0 || yi >= HH || xi < 0 || xi >= WW) return 0.f;
  return xp[yi * WW + xi];
}

__global__ __launch_bounds__(256) void k2f(const float* __restrict__ x,
                                           const float* __restrict__ w_t,
                                           const float* __restrict__ dcn_b,
                                           const float* __restrict__ pyg,
                                           const float* __restrict__ pxg,
                                           const float* __restrict__ mg,
                                           float* __restrict__ out1) {
  int whalf = blockIdx.x, h = blockIdx.y, b = blockIdx.z;
  __shared__ __align__(16) float posS[3 * 288];
  __shared__ __align__(16) float scol[72 * 32];
  __shared__ __align__(16) float wlS[72 * 128];
  int t = threadIdx.x;

  for (int e = t; e < 288; e += 256) {
    int k = e >> 5, wl = e & 31;
    int gi = ((b * 9 + k) * HH + h) * WW + whalf * 32 + wl;
    posS[e] = pyg[gi];
    posS[288 + e] = pxg[gi];
    posS[576 + e] = mg[gi];
  }

  float acc[4][4];
#pragma unroll
  for (int i = 0; i < 4; i++)
#pragma unroll
    for (int j = 0; j < 4; j++) acc[i][j] = 0.f;

  int co0 = (t >> 3) * 4;
  int w0 = (t & 7) * 4;
  const float* xpb = x + b * CINC * HH * WW;

  for (int c0 = 0; c0 < CINC; c0 += 8) {
    __syncthreads();
    const float* wsrc = w_t + c0 * 9 * 128;
    for (int e = t; e < 9216; e += 256) wlS[e] = wsrc[e];
    for (int e = t; e < 2304; e += 256) {
      int ck = e >> 5, wl = e & 31;
      int c = c0 + ck / 9;
      int k = ck % 9;
      float py = posS[k * 32 + wl];
      float px = posS[288 + k * 32 + wl];
      float m = posS[576 + k * 32 + wl];
      float y0f = floorf(py), x0f = floorf(px);
      float wy = py - y0f, wx = px - x0f;
      int y0 = (int)y0f, x0 = (int)x0f;
      const float* xp = xpb + c * HH * WW;
      float v00 = sampf(xp, y0, x0);
      float v01 = sampf(xp, y0, x0 + 1);
      float v10 = sampf(xp, y0 + 1, x0);
      float v11 = sampf(xp, y0 + 1, x0 + 1);
      float v = v00 * (1.f - wy) * (1.f - wx) + v01 * (1.f - wy) * wx +
                v10 * wy * (1.f - wx) + v11 * wy * wx;
      scol[ck * 32 + wl] = v * m;
    }
    __syncthreads();
#pragma unroll 8
    for (int ck = 0; ck < 72; ck++) {
      float4 sv = *(const float4*)&scol[ck * 32 + w0];
      float4 wv = *(const float4*)&wlS[ck * 128 + co0];
      acc[0][0] = fmaf(wv.x, sv.x, acc[0][0]); acc[0][1] = fmaf(wv.x, sv.y, acc[0][1]);
      acc[0][2] = fmaf(wv.x, sv.z, acc[0][2]); acc[0][3] = fmaf(wv.x, sv.w, acc[0][3]);
      acc[1][0] = fmaf(wv.y, sv.x, acc[1][0]); acc[1][1] = fmaf(wv.y, sv.y, acc[1][1]);
      acc[1][2] = fmaf(wv.y, sv.z, acc[1][2]); acc[1][3] = fmaf(wv.y, sv.w, acc[1][3]);
      acc[2][0] = fmaf(wv.z, sv.x, acc[2][0]); acc[2][1] = fmaf(wv.z, sv.y, acc[2][1]);
      acc[2][2] = fmaf(wv.z, sv.z, acc[2][2]); acc[2][3] = fmaf(wv.z, sv.w, acc[2][3]);
      acc[3][0] = fmaf(wv.w, sv.x, acc[3][0]); acc[3][1] = fmaf(wv.w, sv.y, acc[3][1]);
      acc[3][2] = fmaf(wv.w, sv.z, acc[3][2]); acc[3][3] = fmaf(wv.w, sv.w, acc[3][3]);
    }
  }

#pragma unroll
  for (int i = 0; i < 4; i++) {
    float bias = dcn_b[co0 + i];
    float4 o;
    o.x = acc[i][0] + bias; o.y = acc[i][1] + bias;
    o.z = acc[i][2] + bias; o.w = acc[i][3] + bias;
    *(float4*)&out1[((b * COUTC + co0 + i) * HH + h) * WW + whalf * 32 + w0] = o;
  }
}

// ---------------- K3/K5: per-channel two-pass BN stats
__global__ __launch_bounds__(256) void k3_stats1(const float* __restrict__ out1,
                                                 const float* __restrict__ g, const float* __restrict__ bt,
                                                 float* __restrict__ scale, float* __restrict__ shift) {
  int c = blockIdx.x, t = threadIdx.x;
  __shared__ float r1[256];
  __shared__ float muS;
  float s = 0.f;
  for (int e = t; e < BB * HH * WW; e += 256) {
    int b = e >> 12, sp = e & 4095;
    s += out1[(b * COUTC + c) * 4096 + sp];
  }
  r1[t] = s;
  __syncthreads();
  for (int off = 128; off > 0; off >>= 1) {
    if (t < off) r1[t] += r1[t + off];
    __syncthreads();
  }
  if (t == 0) muS = r1[0] / 16384.f;
  __syncthreads();
  float mu = muS;
  __syncthreads();
  float s2 = 0.f;
  for (int e = t; e < BB * HH * WW; e += 256) {
    int b = e >> 12, sp = e & 4095;
    float d = out1[(b * COUTC + c) * 4096 + sp] - mu;
    s2 += d * d;
  }
  r1[t] = s2;
  __syncthreads();
  for (int off = 128; off > 0; off >>= 1) {
    if (t < off) r1[t] += r1[t + off];
    __syncthreads();
  }
  if (t == 0) {
    float var = r1[0] / 16384.f;
    float sc = g[c] * rsqrtf(var + 1e-5f);
    scale[c] = sc;
    shift[c] = bt[c] - mu * sc;
  }
}

__global__ __launch_bounds__(256) void k5_stats2(const float* __restrict__ out2,
                                                 const float* __restrict__ g, const float* __restrict__ bt,
                                                 float* __restrict__ scale, float* __restrict__ shift) {
  int c = blockIdx.x, t = threadIdx.x;
  __shared__ float r1[256];
  __shared__ float muS;
  float s = 0.f;
  for (int e = t; e < BB * OHH * OWW; e += 256) {
    int b = e >> 14, sp = e & 16383;
    s += out2[(b * COUTC + c) * 16384 + sp];
  }
  r1[t] = s;
  __syncthreads();
  for (int off = 128; off > 0; off >>= 1) {
    if (t < off) r1[t] += r1[t + off];
    __syncthreads();
  }
  if (t == 0) muS = r1[0] / 65536.f;
  __syncthreads();
  float mu = muS;
  __syncthreads();
  float s2 = 0.f;
  for (int e = t; e < BB * OHH * OWW; e += 256) {
    int b = e >> 14, sp = e & 16383;
    float d = out2[(b * COUTC + c) * 16384 + sp] - mu;
    s2 += d * d;
  }
  r1[t] = s2;
  __syncthreads();
  for (int off = 128; off > 0; off >>= 1) {
    if (t < off) r1[t] += r1[t + off];
    __syncthreads();
  }
  if (t == 0) {
    float var = r1[0] / 65536.f;
    float sc = g[c] * rsqrtf(var + 1e-5f);
    scale[c] = sc;
    shift[c] = bt[c] - mu * sc;
  }
}

// ---------------- K4f: bn1+relu fused transposed conv (tiled, parity-decomposed).
__global__ __launch_bounds__(256) void k4f(const float* __restrict__ out1,
                                           const float* __restrict__ s1,
                                           const float* __restrict__ sh1,
                                           const float* __restrict__ wt4,
                                           float* __restrict__ out2) {
  int oh = blockIdx.x, b = blockIdx.y;
  __shared__ __align__(16) float ys[2 * 128 * 64];  // exactly 64 KiB
  int t = threadIdx.x;
  int t0 = oh & 1;

#pragma unroll
  for (int ti = 0; ti < 2; ti++) {
    int tt = t0 + 2 * ti;
    int m = (oh + tt - 2) / 2;
    bool rowok = (m >= 0 && m < 64);
    for (int e = t; e < 2048; e += 256) {
      int i = e >> 4;
      float4 v = make_float4(0.f, 0.f, 0.f, 0.f);
      if (rowok) {
        float4 r = *(const float4*)&out1[((b * COUTC + i) * HH + m) * WW + (e & 15) * 4];
        float sc = s1[i], sh = sh1[i];
        v.x = fmaxf(fmaf(r.x, sc, sh), 0.f);
        v.y = fmaxf(fmaf(r.y, sc, sh), 0.f);
        v.z = fmaxf(fmaf(r.z, sc, sh), 0.f);
        v.w = fmaxf(fmaf(r.w, sc, sh), 0.f);
      }
      *(float4*)&ys[ti * 8192 + e * 4] = v;
    }
  }
  __syncthreads();

  int o = t >> 1, half = t & 1;
  int nb = half * 32;
  float acc[64];
#pragma unroll
  for (int j = 0; j < 64; j++) acc[j] = 0.f;

  const float* wb0 = wt4 + ((t0 * 128) * 128 + o) * 4;
  const float* wb1 = wt4 + (((t0 + 2) * 128) * 128 + o) * 4;

  for (int i = 0; i < 128; i++) {
#pragma unroll
    for (int ti = 0; ti < 2; ti++) {
      float4 wv = *(const float4*)((ti ? wb1 : wb0) + i * 512);
      float W0 = wv.x, W1 = wv.y, W2 = wv.z, W3 = wv.w;

      const float* yb = &ys[ti * 8192 + i * 64 + nb];
      float yv[34];
#pragma unroll
      for (int j4 = 0; j4 < 8; j4++) {
        float4 q4 = *(const float4*)(yb + 4 * j4);
        yv[1 + 4 * j4] = q4.x; yv[2 + 4 * j4] = q4.y;
        yv[3 + 4 * j4] = q4.z; yv[4 + 4 * j4] = q4.w;
      }
      yv[0]  = half ? yb[-1] : 0.f;
      yv[33] = half ? 0.f : yb[32];
#pragma unroll
      for (int u = 0; u < 32; u++) {
        acc[2 * u]     = fmaf(W0, yv[u],     fmaf(W2, yv[u + 1], acc[2 * u]));
        acc[2 * u + 1] = fmaf(W1, yv[u + 1], fmaf(W3, yv[u + 2], acc[2 * u + 1]));
      }
    }
  }

  float* op = out2 + ((b * COUTC + o) * OHH + oh) * OWW + half * 64;
#pragma unroll
  for (int j4 = 0; j4 < 16; j4++) {
    float4 v;
    v.x = acc[4 * j4]; v.y = acc[4 * j4 + 1]; v.z = acc[4 * j4 + 2]; v.w = acc[4 * j4 + 3];
    *(float4*)&op[4 * j4] = v;
  }
}

// ---------------- K6: bn2+relu apply (f32 out)
__global__ __launch_bounds__(256) void k6s(const float* __restrict__ out2,
                                           const float* __restrict__ scale2,
                                           const float* __restrict__ shift2,
                                           float* __restrict__ outp) {
  int tid = blockIdx.x * 256 + threadIdx.x;
  if (tid >= BB * COUTC * OHH * OWW) return;
  int c = (tid >> 14) & 127;
  outp[tid] = fmaxf(fmaf(out2[tid], scale2[c], shift2[c]), 0.f);
}

// ---------------- launch
extern "C" void kernel_launch(void* const* d_in, const int* in_sizes, int n_in,
                              void* d_out, int out_size, void* d_ws, size_t ws_size,
                              hipStream_t stream) {
  const float* x     = (const float*)d_in[0];
  const float* off_w = (const float*)d_in[1];
  const float* off_b = (const float*)d_in[2];
  const float* dcn_w = (const float*)d_in[3];
  const float* dcn_b = (const float*)d_in[4];
  const float* bn1_g = (const float*)d_in[5];
  const float* bn1_b = (const float*)d_in[6];
  const float* up_w  = (const float*)d_in[7];
  const float* bn2_g = (const float*)d_in[8];
  const float* bn2_b = (const float*)d_in[9];

  float* ws = (float*)d_ws;
  float* pyg  = ws;                              // 147456
  float* pxg  = pyg + BB * 9 * HH * WW;          // 147456
  float* mg   = pxg + BB * 9 * HH * WW;          // 147456
  float* out1 = mg + BB * 9 * HH * WW;           // 2097152
  float* scale1 = out1 + BB * COUTC * HH * WW;   // 128
  float* shift1 = scale1 + 128;                  // 128
  float* out2 = shift1 + 128;                    // 8388608
  float* scale2 = out2 + BB * COUTC * OHH * OWW; // 128
  float* shift2 = scale2 + 128;                  // 128
  float* w_t = shift2 + 128;                     // 294912
  float* wt4 = w_t + COUTC * CINC * 9;           // 262144
  // k1 partials (4*4*27*4096 = 1,769,472 floats) overlaid on out2 region:
  // written by k1p, consumed by k1r, both complete before k4f writes out2.
  float* part = out2;

  const int N4 = BB * COUTC * OHH * OWW;  // 8388608
  const int N1 = BB * 27 * HH * WW;       // 442368

  k0t<<<(COUTC * CINC * 9 + 255) / 256, 256, 0, stream>>>(dcn_w, w_t);
  k0u<<<(4 * COUTC * COUTC * 4 + 255) / 256, 256, 0, stream>>>(up_w, wt4);
  k1p<<<dim3(4, 64, 4), 256, 0, stream>>>(x, off_w, part);
  k1r<<<(N1 + 255) / 256, 256, 0, stream>>>(part, off_b, pyg, pxg, mg);
  k2f<<<dim3(2, 64, 4), 256, 0, stream>>>(x, w_t, dcn_b, pyg, pxg, mg, out1);
  k3_stats1<<<COUTC, 256, 0, stream>>>(out1, bn1_g, bn1_b, scale1, shift1);
  k4f<<<dim3(128, 4), 256, 0, stream>>>(out1, scale1, shift1, wt4, out2);
  k5_stats2<<<COUTC, 256, 0, stream>>>(out2, bn2_g, bn2_b, scale2, shift2);
  k6s<<<(N4 + 255) / 256, 256, 0, stream>>>(out2, scale2, shift2, (float*)d_out);
}

// Round 8
// 735.807 us; speedup vs baseline: 18.6669x; 1.0454x over previous
//
#include <hip/hip_runtime.h>
#include <math.h>

// Problem constants
#define BB 4
#define CINC 256
#define COUTC 128
#define HH 64
#define WW 64
#define OHH 128
#define OWW 128

// ---------------- K0t: transpose dcn_w [o][c][q] -> w_t[(c*9+q)][o]
__global__ __launch_bounds__(256) void k0t(const float* __restrict__ dcn_w, float* __restrict__ w_t) {
  int tid = blockIdx.x * 256 + threadIdx.x;
  if (tid >= COUTC * CINC * 9) return;
  int ck = tid >> 7;
  int o = tid & 127;
  w_t[tid] = dcn_w[o * (CINC * 9) + ck];
}

// ---------------- K0u: transpose up_w -> wt4[tt][i][o][s]
__global__ __launch_bounds__(256) void k0u(const float* __restrict__ up_w, float* __restrict__ wt4) {
  int tid = blockIdx.x * 256 + threadIdx.x;
  if (tid >= 4 * COUTC * COUTC * 4) return;
  int s = tid & 3;
  int o = (tid >> 2) & 127;
  int i = (tid >> 9) & 127;
  int tt = tid >> 16;
  wt4[tid] = up_w[((i * COUTC + o) * 4 + (3 - tt)) * 4 + (3 - s)];
}

// ---------------- K1p: offset conv split-K partials. grid (4,64,4)=(cc,h,b), 256 thr.
__global__ __launch_bounds__(256) void k1p(const float* __restrict__ x,
                                           const float* __restrict__ off_w,
                                           float* __restrict__ part) {
  int cc = blockIdx.x, h = blockIdx.y, b = blockIdx.z;
  __shared__ float xs[3 * 32 * 66];
  int t = threadIdx.x;
  int tw = t & 63;
  int tg = __builtin_amdgcn_readfirstlane(t >> 6);

  float acc[7];
#pragma unroll
  for (int j = 0; j < 7; j++) acc[j] = 0.f;

  for (int cs = 0; cs < 2; cs++) {
    int c0 = cc * 64 + cs * 32;
    __syncthreads();
    for (int e = t; e < 3 * 32 * 66; e += 256) {
      int r = e / (32 * 66);
      int rem = e - r * (32 * 66);
      int c = rem / 66;
      int wi = rem - c * 66;
      int row = h - 1 + r;
      int col = wi - 1;
      float v = 0.f;
      if (row >= 0 && row < HH && col >= 0 && col < WW)
        v = x[((b * CINC + c0 + c) * HH + row) * WW + col];
      xs[(r * 32 + c) * 66 + wi] = v;
    }
    __syncthreads();
    for (int c = 0; c < 32; c++) {
      float xv[9];
#pragma unroll
      for (int r = 0; r < 3; r++)
#pragma unroll
        for (int dx = 0; dx < 3; dx++)
          xv[r * 3 + dx] = xs[(r * 32 + c) * 66 + tw + dx];
#pragma unroll
      for (int j = 0; j < 7; j++) {
        int oc = tg + 4 * j;
        if (oc < 27) {
          const float* wp = off_w + (oc * CINC + c0 + c) * 9;  // uniform -> s_load
#pragma unroll
          for (int q = 0; q < 9; q++) acc[j] = fmaf(xv[q], wp[q], acc[j]);
        }
      }
    }
  }

#pragma unroll
  for (int j = 0; j < 7; j++) {
    int oc = tg + 4 * j;
    if (oc < 27)
      part[((cc * BB + b) * 27 + oc) * 4096 + h * 64 + tw] = acc[j];
  }
}

// ---------------- K1r: reduce 4 partials + bias -> py/px/m
__global__ __launch_bounds__(256) void k1r(const float* __restrict__ part,
                                           const float* __restrict__ off_b,
                                           float* __restrict__ pyg,
                                           float* __restrict__ pxg,
                                           float* __restrict__ mg) {
  int tid = blockIdx.x * 256 + threadIdx.x;
  if (tid >= BB * 27 * HH * WW) return;
  int w = tid & 63;
  int h = (tid >> 6) & 63;
  int oc = (tid >> 12) % 27;
  int b = tid / (27 * 4096);
  int sp = tid & 4095;

  float v = off_b[oc];
#pragma unroll
  for (int cc = 0; cc < 4; cc++)
    v += part[((cc * BB + b) * 27 + oc) * 4096 + sp];

  int k = oc % 9;
  int gi = ((b * 9 + k) * HH + h) * WW + w;
  if (oc < 9) {
    pyg[gi] = v + (float)(oc / 3) - 1.f + (float)h;
  } else if (oc < 18) {
    pxg[gi] = v + (float)((oc - 9) % 3) - 1.f + (float)w;
  } else {
    mg[gi] = 1.f / (1.f + expf(-v));
  }
}

// ---------------- K2p: deformable conv, split-K tiled GEMM. grid (2,64,4)=(ks,h,b).
// Block: 64 px (row h) x 128 cout x 128 input channels (16 chunks of 8).
// Thread tile: 8 cout x 4 px. Partials to part2 (summed in k2r).
__device__ __forceinline__ float sampf(const float* __restrict__ xp, int yi, int xi) {
  if (yi < 0 || yi >= HH || xi < 0 || xi >= WW) return 0.f;
  return xp[yi * WW + xi];
}

__global__ __launch_bounds__(256) void k2p(const float* __restrict__ x,
                                           const float* __restrict__ w_t,
                                           const float* __restrict__ pyg,
                                           const float* __restrict__ pxg,
                                           const float* __restrict__ mg,
                                           float* __restrict__ part2) {
  int ks = blockIdx.x, h = blockIdx.y, b = blockIdx.z;
  __shared__ __align__(16) float posS[3 * 576];   // py | px | m, each [9][64]
  __shared__ __align__(16) float scol[72 * 64];   // (8ch x 9k) x 64 px
  __shared__ __align__(16) float wlS[72 * 128];   // 72 ck x 128 cout
  int t = threadIdx.x;

  for (int e = t; e < 576; e += 256) {
    int k = e >> 6, wl = e & 63;
    int gi = ((b * 9 + k) * HH + h) * WW + wl;
    posS[e] = pyg[gi];
    posS[576 + e] = pxg[gi];
    posS[1152 + e] = mg[gi];
  }

  float acc[8][4];
#pragma unroll
  for (int i = 0; i < 8; i++)
#pragma unroll
    for (int j = 0; j < 4; j++) acc[i][j] = 0.f;

  int co0 = (t >> 4) * 8;   // 0..120
  int w0 = (t & 15) * 4;    // 0..60
  const float* xpb = x + b * CINC * HH * WW;

  for (int cs = 0; cs < 16; cs++) {
    int c0 = ks * 128 + cs * 8;
    __syncthreads();
    // ---- bulk register prefetch: weights (36) ----
    const float* wsrc = w_t + c0 * 9 * 128;
    float wreg[36];
#pragma unroll
    for (int j = 0; j < 36; j++) wreg[j] = wsrc[t + 256 * j];
    // ---- gather samples into regs (18) ----
    float sreg[18];
#pragma unroll
    for (int j = 0; j < 18; j++) {
      int e = t + 256 * j;
      int ck = e >> 6, wl = e & 63;
      int c = c0 + ck / 9;
      int k = ck % 9;
      float py = posS[k * 64 + wl];
      float px = posS[576 + k * 64 + wl];
      float m = posS[1152 + k * 64 + wl];
      float y0f = floorf(py), x0f = floorf(px);
      float wy = py - y0f, wx = px - x0f;
      int y0 = (int)y0f, x0 = (int)x0f;
      const float* xp = xpb + c * HH * WW;
      float v00 = sampf(xp, y0, x0);
      float v01 = sampf(xp, y0, x0 + 1);
      float v10 = sampf(xp, y0 + 1, x0);
      float v11 = sampf(xp, y0 + 1, x0 + 1);
      float v = v00 * (1.f - wy) * (1.f - wx) + v01 * (1.f - wy) * wx +
                v10 * wy * (1.f - wx) + v11 * wy * wx;
      sreg[j] = v * m;
    }
    // ---- commit to LDS ----
#pragma unroll
    for (int j = 0; j < 36; j++) wlS[t + 256 * j] = wreg[j];
#pragma unroll
    for (int j = 0; j < 18; j++) scol[t + 256 * j] = sreg[j];
    __syncthreads();
    // ---- compute: 72 ck x (8 cout x 4 px) ----
#pragma unroll 4
    for (int ck = 0; ck < 72; ck++) {
      float4 sv = *(const float4*)&scol[ck * 64 + w0];
      float4 wva = *(const float4*)&wlS[ck * 128 + co0];
      float4 wvb = *(const float4*)&wlS[ck * 128 + co0 + 4];
      acc[0][0] = fmaf(wva.x, sv.x, acc[0][0]); acc[0][1] = fmaf(wva.x, sv.y, acc[0][1]);
      acc[0][2] = fmaf(wva.x, sv.z, acc[0][2]); acc[0][3] = fmaf(wva.x, sv.w, acc[0][3]);
      acc[1][0] = fmaf(wva.y, sv.x, acc[1][0]); acc[1][1] = fmaf(wva.y, sv.y, acc[1][1]);
      acc[1][2] = fmaf(wva.y, sv.z, acc[1][2]); acc[1][3] = fmaf(wva.y, sv.w, acc[1][3]);
      acc[2][0] = fmaf(wva.z, sv.x, acc[2][0]); acc[2][1] = fmaf(wva.z, sv.y, acc[2][1]);
      acc[2][2] = fmaf(wva.z, sv.z, acc[2][2]); acc[2][3] = fmaf(wva.z, sv.w, acc[2][3]);
      acc[3][0] = fmaf(wva.w, sv.x, acc[3][0]); acc[3][1] = fmaf(wva.w, sv.y, acc[3][1]);
      acc[3][2] = fmaf(wva.w, sv.z, acc[3][2]); acc[3][3] = fmaf(wva.w, sv.w, acc[3][3]);
      acc[4][0] = fmaf(wvb.x, sv.x, acc[4][0]); acc[4][1] = fmaf(wvb.x, sv.y, acc[4][1]);
      acc[4][2] = fmaf(wvb.x, sv.z, acc[4][2]); acc[4][3] = fmaf(wvb.x, sv.w, acc[4][3]);
      acc[5][0] = fmaf(wvb.y, sv.x, acc[5][0]); acc[5][1] = fmaf(wvb.y, sv.y, acc[5][1]);
      acc[5][2] = fmaf(wvb.y, sv.z, acc[5][2]); acc[5][3] = fmaf(wvb.y, sv.w, acc[5][3]);
      acc[6][0] = fmaf(wvb.z, sv.x, acc[6][0]); acc[6][1] = fmaf(wvb.z, sv.y, acc[6][1]);
      acc[6][2] = fmaf(wvb.z, sv.z, acc[6][2]); acc[6][3] = fmaf(wvb.z, sv.w, acc[6][3]);
      acc[7][0] = fmaf(wvb.w, sv.x, acc[7][0]); acc[7][1] = fmaf(wvb.w, sv.y, acc[7][1]);
      acc[7][2] = fmaf(wvb.w, sv.z, acc[7][2]); acc[7][3] = fmaf(wvb.w, sv.w, acc[7][3]);
    }
  }

  // write partials: part2[ks][b][o][h*64+w]
  float* pb = part2 + ((size_t)ks * BB * COUTC) * 4096;
#pragma unroll
  for (int i = 0; i < 8; i++) {
    float4 o;
    o.x = acc[i][0]; o.y = acc[i][1]; o.z = acc[i][2]; o.w = acc[i][3];
    *(float4*)&pb[((b * COUTC + co0 + i) * HH + h) * WW + w0] = o;
  }
}

// ---------------- K2r: sum 2 partials + bias -> out1
__global__ __launch_bounds__(256) void k2r(const float* __restrict__ part2,
                                           const float* __restrict__ dcn_b,
                                           float* __restrict__ out1) {
  int tid = blockIdx.x * 256 + threadIdx.x;
  if (tid >= BB * COUTC * HH * WW) return;
  int o = (tid >> 12) & 127;
  out1[tid] = part2[tid] + part2[tid + BB * COUTC * 4096] + dcn_b[o];
}

// ---------------- K3/K5: per-channel two-pass BN stats
__global__ __launch_bounds__(256) void k3_stats1(const float* __restrict__ out1,
                                                 const float* __restrict__ g, const float* __restrict__ bt,
                                                 float* __restrict__ scale, float* __restrict__ shift) {
  int c = blockIdx.x, t = threadIdx.x;
  __shared__ float r1[256];
  __shared__ float muS;
  float s = 0.f;
  for (int e = t; e < BB * HH * WW; e += 256) {
    int b = e >> 12, sp = e & 4095;
    s += out1[(b * COUTC + c) * 4096 + sp];
  }
  r1[t] = s;
  __syncthreads();
  for (int off = 128; off > 0; off >>= 1) {
    if (t < off) r1[t] += r1[t + off];
    __syncthreads();
  }
  if (t == 0) muS = r1[0] / 16384.f;
  __syncthreads();
  float mu = muS;
  __syncthreads();
  float s2 = 0.f;
  for (int e = t; e < BB * HH * WW; e += 256) {
    int b = e >> 12, sp = e & 4095;
    float d = out1[(b * COUTC + c) * 4096 + sp] - mu;
    s2 += d * d;
  }
  r1[t] = s2;
  __syncthreads();
  for (int off = 128; off > 0; off >>= 1) {
    if (t < off) r1[t] += r1[t + off];
    __syncthreads();
  }
  if (t == 0) {
    float var = r1[0] / 16384.f;
    float sc = g[c] * rsqrtf(var + 1e-5f);
    scale[c] = sc;
    shift[c] = bt[c] - mu * sc;
  }
}

__global__ __launch_bounds__(256) void k5_stats2(const float* __restrict__ out2,
                                                 const float* __restrict__ g, const float* __restrict__ bt,
                                                 float* __restrict__ scale, float* __restrict__ shift) {
  int c = blockIdx.x, t = threadIdx.x;
  __shared__ float r1[256];
  __shared__ float muS;
  float s = 0.f;
  for (int e = t; e < BB * OHH * OWW; e += 256) {
    int b = e >> 14, sp = e & 16383;
    s += out2[(b * COUTC + c) * 16384 + sp];
  }
  r1[t] = s;
  __syncthreads();
  for (int off = 128; off > 0; off >>= 1) {
    if (t < off) r1[t] += r1[t + off];
    __syncthreads();
  }
  if (t == 0) muS = r1[0] / 65536.f;
  __syncthreads();
  float mu = muS;
  __syncthreads();
  float s2 = 0.f;
  for (int e = t; e < BB * OHH * OWW; e += 256) {
    int b = e >> 14, sp = e & 16383;
    float d = out2[(b * COUTC + c) * 16384 + sp] - mu;
    s2 += d * d;
  }
  r1[t] = s2;
  __syncthreads();
  for (int off = 128; off > 0; off >>= 1) {
    if (t < off) r1[t] += r1[t + off];
    __syncthreads();
  }
  if (t == 0) {
    float var = r1[0] / 65536.f;
    float sc = g[c] * rsqrtf(var + 1e-5f);
    scale[c] = sc;
    shift[c] = bt[c] - mu * sc;
  }
}

// ---------------- K4f: bn1+relu fused transposed conv (tiled, parity-decomposed).
__global__ __launch_bounds__(256) void k4f(const float* __restrict__ out1,
                                           const float* __restrict__ s1,
                                           const float* __restrict__ sh1,
                                           const float* __restrict__ wt4,
                                           float* __restrict__ out2) {
  int oh = blockIdx.x, b = blockIdx.y;
  __shared__ __align__(16) float ys[2 * 128 * 64];  // exactly 64 KiB
  int t = threadIdx.x;
  int t0 = oh & 1;

#pragma unroll
  for (int ti = 0; ti < 2; ti++) {
    int tt = t0 + 2 * ti;
    int m = (oh + tt - 2) / 2;
    bool rowok = (m >= 0 && m < 64);
    for (int e = t; e < 2048; e += 256) {
      int i = e >> 4;
      float4 v = make_float4(0.f, 0.f, 0.f, 0.f);
      if (rowok) {
        float4 r = *(const float4*)&out1[((b * COUTC + i) * HH + m) * WW + (e & 15) * 4];
        float sc = s1[i], sh = sh1[i];
        v.x = fmaxf(fmaf(r.x, sc, sh), 0.f);
        v.y = fmaxf(fmaf(r.y, sc, sh), 0.f);
        v.z = fmaxf(fmaf(r.z, sc, sh), 0.f);
        v.w = fmaxf(fmaf(r.w, sc, sh), 0.f);
      }
      *(float4*)&ys[ti * 8192 + e * 4] = v;
    }
  }
  __syncthreads();

  int o = t >> 1, half = t & 1;
  int nb = half * 32;
  float acc[64];
#pragma unroll
  for (int j = 0; j < 64; j++) acc[j] = 0.f;

  const float* wb0 = wt4 + ((t0 * 128) * 128 + o) * 4;
  const float* wb1 = wt4 + (((t0 + 2) * 128) * 128 + o) * 4;

  for (int i = 0; i < 128; i++) {
#pragma unroll
    for (int ti = 0; ti < 2; ti++) {
      float4 wv = *(const float4*)((ti ? wb1 : wb0) + i * 512);
      float W0 = wv.x, W1 = wv.y, W2 = wv.z, W3 = wv.w;

      const float* yb = &ys[ti * 8192 + i * 64 + nb];
      float yv[34];
#pragma unroll
      for (int j4 = 0; j4 < 8; j4++) {
        float4 q4 = *(const float4*)(yb + 4 * j4);
        yv[1 + 4 * j4] = q4.x; yv[2 + 4 * j4] = q4.y;
        yv[3 + 4 * j4] = q4.z; yv[4 + 4 * j4] = q4.w;
      }
      yv[0]  = half ? yb[-1] : 0.f;
      yv[33] = half ? 0.f : yb[32];
#pragma unroll
      for (int u = 0; u < 32; u++) {
        acc[2 * u]     = fmaf(W0, yv[u],     fmaf(W2, yv[u + 1], acc[2 * u]));
        acc[2 * u + 1] = fmaf(W1, yv[u + 1], fmaf(W3, yv[u + 2], acc[2 * u + 1]));
      }
    }
  }

  float* op = out2 + ((b * COUTC + o) * OHH + oh) * OWW + half * 64;
#pragma unroll
  for (int j4 = 0; j4 < 16; j4++) {
    float4 v;
    v.x = acc[4 * j4]; v.y = acc[4 * j4 + 1]; v.z = acc[4 * j4 + 2]; v.w = acc[4 * j4 + 3];
    *(float4*)&op[4 * j4] = v;
  }
}

// ---------------- K6: bn2+relu apply (f32 out)
__global__ __launch_bounds__(256) void k6s(const float* __restrict__ out2,
                                           const float* __restrict__ scale2,
                                           const float* __restrict__ shift2,
                                           float* __restrict__ outp) {
  int tid = blockIdx.x * 256 + threadIdx.x;
  if (tid >= BB * COUTC * OHH * OWW) return;
  int c = (tid >> 14) & 127;
  outp[tid] = fmaxf(fmaf(out2[tid], scale2[c], shift2[c]), 0.f);
}

// ---------------- launch
extern "C" void kernel_launch(void* const* d_in, const int* in_sizes, int n_in,
                              void* d_out, int out_size, void* d_ws, size_t ws_size,
                              hipStream_t stream) {
  const float* x     = (const float*)d_in[0];
  const float* off_w = (const float*)d_in[1];
  const float* off_b = (const float*)d_in[2];
  const float* dcn_w = (const float*)d_in[3];
  const float* dcn_b = (const float*)d_in[4];
  const float* bn1_g = (const float*)d_in[5];
  const float* bn1_b = (const float*)d_in[6];
  const float* up_w  = (const float*)d_in[7];
  const float* bn2_g = (const float*)d_in[8];
  const float* bn2_b = (const float*)d_in[9];

  float* ws = (float*)d_ws;
  float* pyg  = ws;                              // 147456
  float* pxg  = pyg + BB * 9 * HH * WW;          // 147456
  float* mg   = pxg + BB * 9 * HH * WW;          // 147456
  float* out1 = mg + BB * 9 * HH * WW;           // 2097152
  float* scale1 = out1 + BB * COUTC * HH * WW;   // 128
  float* shift1 = scale1 + 128;                  // 128
  float* out2 = shift1 + 128;                    // 8388608
  float* scale2 = out2 + BB * COUTC * OHH * OWW; // 128
  float* shift2 = scale2 + 128;                  // 128
  float* w_t = shift2 + 128;                     // 294912
  float* wt4 = w_t + COUTC * CINC * 9;           // 262144
  float* part2 = wt4 + 4 * COUTC * COUTC * 4;    // 2 * 2097152
  // k1 partials overlaid on out2 region (k1p/k1r complete before k4f writes out2)
  float* part = out2;

  const int N4 = BB * COUTC * OHH * OWW;  // 8388608
  const int N2 = BB * COUTC * HH * WW;    // 2097152
  const int N1 = BB * 27 * HH * WW;       // 442368

  k0t<<<(COUTC * CINC * 9 + 255) / 256, 256, 0, stream>>>(dcn_w, w_t);
  k0u<<<(4 * COUTC * COUTC * 4 + 255) / 256, 256, 0, stream>>>(up_w, wt4);
  k1p<<<dim3(4, 64, 4), 256, 0, stream>>>(x, off_w, part);
  k1r<<<(N1 + 255) / 256, 256, 0, stream>>>(part, off_b, pyg, pxg, mg);
  k2p<<<dim3(2, 64, 4), 256, 0, stream>>>(x, w_t, pyg, pxg, mg, part2);
  k2r<<<(N2 + 255) / 256, 256, 0, stream>>>(part2, dcn_b, out1);
  k3_stats1<<<COUTC, 256, 0, stream>>>(out1, bn1_g, bn1_b, scale1, shift1);
  k4f<<<dim3(128, 4), 256, 0, stream>>>(out1, scale1, shift1, wt4, out2);
  k5_stats2<<<COUTC, 256, 0, stream>>>(out2, bn2_g, bn2_b, scale2, shift2);
  k6s<<<(N4 + 255) / 256, 256, 0, stream>>>(out2, scale2, shift2, (float*)d_out);
}